// Round 17
// baseline (1776.787 us; speedup 1.0000x reference)
//
#include <hip/hip_runtime.h>
#include <math.h>

// ---------------------------------------------------------------------------
// FeatureEncoder R17 = R16 (best, 1445us) + two independent deltas:
//  (1) L4 convT prefetch depth ICB 4->8 (32 loads in flight; L4 is
//      grid-limited at 1024 blocks so VGPR growth costs no occupancy).
//  (2) conv7_fin folded into seg_accum (reads the 4 ic-split partials +
//      bias + tanh inline; a7 never materialized; one fewer pass+launch).
// ---------------------------------------------------------------------------

#define IDIV(a, b) (((a) + (b) - 1) / (b))

__device__ __forceinline__ int reflect_i(int i, int n) {
    i = i < 0 ? -i : i;
    return i >= n ? 2 * n - 2 - i : i;
}

// block-level (sum,sumsq) reduction for OCPT channels -> partial store
template <int OCPT>
__device__ __forceinline__ void stats_block_store(
    const float* sv, const float* ssv, float* __restrict__ spart,
    float* __restrict__ sspart, int P, int tile, int pc0) {
    __shared__ float redS[OCPT], redSS[OCPT];
    if (threadIdx.x < OCPT) { redS[threadIdx.x] = 0.f; redSS[threadIdx.x] = 0.f; }
    __syncthreads();
    int lane = threadIdx.x & 63;
#pragma unroll
    for (int j = 0; j < OCPT; ++j) {
        float s = sv[j], ss = ssv[j];
#pragma unroll
        for (int o = 32; o > 0; o >>= 1) {
            s += __shfl_down(s, o);
            ss += __shfl_down(ss, o);
        }
        if (lane == 0) { atomicAdd(&redS[j], s); atomicAdd(&redSS[j], ss); }  // LDS atomics
    }
    __syncthreads();
    if (threadIdx.x < OCPT) {
        spart[(size_t)tile * P + pc0 + threadIdx.x] = redS[threadIdx.x];
        sspart[(size_t)tile * P + pc0 + threadIdx.x] = redSS[threadIdx.x];
    }
}

// fold [nT][P] partials -> mean, inv (one wavefront per plane)
__global__ __launch_bounds__(64) void stat_reduce_mi(
    const float* __restrict__ sp, const float* __restrict__ ssp,
    float* __restrict__ mean, float* __restrict__ inv, int P, int nT,
    float rcp_plane) {
    int p = blockIdx.x;
    float a = 0.f, bsum = 0.f;
    for (int t = threadIdx.x; t < nT; t += 64) {
        a += sp[(size_t)t * P + p];
        bsum += ssp[(size_t)t * P + p];
    }
#pragma unroll
    for (int o = 32; o > 0; o >>= 1) {
        a += __shfl_down(a, o);
        bsum += __shfl_down(bsum, o);
    }
    if (threadIdx.x == 0) {
        float m = a * rcp_plane;
        float var = bsum * rcp_plane - m * m;
        mean[p] = m;
        inv[p] = rsqrtf(var + 1e-5f);
    }
}

// ---------------- 7x7 same-conv (L0: raw input), fused stats ----------------
template <int CIN, int OCPT>
__global__ __launch_bounds__(256) void conv7_v3s(
    const float* __restrict__ x, const float* __restrict__ w,
    const float* __restrict__ b, float* __restrict__ y,
    float* __restrict__ spart, float* __restrict__ sspart, int P,
    int Cout, int H, int W) {
    int tx = threadIdx.x & 15, ty = threadIdx.x >> 4;
    int tilesX = IDIV(W, 16);
    int ow = (blockIdx.x % tilesX) * 16 + tx;
    int oh = (blockIdx.x / tilesX) * 16 + ty;
    int oc0 = blockIdx.y * OCPT;
    int n = blockIdx.z;
    // exact-fit grid: no early return (barrier safety)

    int offr[7], iws[7];
#pragma unroll
    for (int k = 0; k < 7; ++k) {
        offr[k] = reflect_i(oh + k - 3, H) * W;
        iws[k] = reflect_i(ow + k - 3, W);
    }

    float acc[OCPT];
#pragma unroll
    for (int j = 0; j < OCPT; ++j) acc[j] = 0.f;

    const float* xn = x + (size_t)n * CIN * H * W;
    for (int ic = 0; ic < CIN; ++ic) {
        const float* xp = xn + (size_t)ic * H * W;
        float v[49];
#pragma unroll
        for (int kh = 0; kh < 7; ++kh) {
#pragma unroll
            for (int kw = 0; kw < 7; ++kw)
                v[kh * 7 + kw] = xp[offr[kh] + iws[kw]];
        }
        const float* wp = w + ((size_t)oc0 * CIN + ic) * 49;
#pragma unroll
        for (int j = 0; j < OCPT; ++j) {
#pragma unroll
            for (int t = 0; t < 49; ++t)
                acc[j] += v[t] * wp[(size_t)j * CIN * 49 + t];
        }
    }
    float sv[OCPT], ssv[OCPT];
#pragma unroll
    for (int j = 0; j < OCPT; ++j) {
        float r = acc[j] + b[oc0 + j];
        y[(((size_t)n * Cout + oc0 + j) * H + oh) * W + ow] = r;
        sv[j] = r;
        ssv[j] = r * r;
    }
    stats_block_store<OCPT>(sv, ssv, spart, sspart, P, blockIdx.x, n * Cout + oc0);
}

// ---------------- 7x7 conv, ic-split partial (L7) ----------------
template <int CINTOT, int ICPB, int OCPT>
__global__ __launch_bounds__(256) void conv7_part(
    const float* __restrict__ x, const float* __restrict__ w,
    float* __restrict__ part, size_t PS, int H, int W) {
    int tx = threadIdx.x & 15, ty = threadIdx.x >> 4;
    int tilesX = IDIV(W, 16);
    int ow = (blockIdx.x % tilesX) * 16 + tx;
    int oh = (blockIdx.x / tilesX) * 16 + ty;
    int ks = blockIdx.y;
    int n = blockIdx.z;
    if (ow >= W || oh >= H) return;

    int offr[7], iws[7];
#pragma unroll
    for (int k = 0; k < 7; ++k) {
        offr[k] = reflect_i(oh + k - 3, H) * W;
        iws[k] = reflect_i(ow + k - 3, W);
    }

    float acc[OCPT];
#pragma unroll
    for (int j = 0; j < OCPT; ++j) acc[j] = 0.f;

    const float* xn = x + (size_t)n * CINTOT * H * W;
    const int ic0 = ks * ICPB;
    for (int icl = 0; icl < ICPB; ++icl) {
        int ic = ic0 + icl;
        const float* xp = xn + (size_t)ic * H * W;
        float v[49];
#pragma unroll
        for (int kh = 0; kh < 7; ++kh) {
#pragma unroll
            for (int kw = 0; kw < 7; ++kw)
                v[kh * 7 + kw] = xp[offr[kh] + iws[kw]];
        }
        const float* wp = w + (size_t)ic * 49;
#pragma unroll
        for (int j = 0; j < OCPT; ++j) {
#pragma unroll
            for (int t = 0; t < 49; ++t)
                acc[j] += v[t] * wp[(size_t)j * CINTOT * 49 + t];
        }
    }
#pragma unroll
    for (int j = 0; j < OCPT; ++j)
        part[(size_t)ks * PS + (((size_t)n * OCPT + j) * H + oh) * W + ow] = acc[j];
}

// ---------------- 3x3 s2 conv, branchless batched loads, fused stats --------
template <int CIN, int ICB, int OCPT>
__global__ __launch_bounds__(256) void conv3s2_v3s(
    const float* __restrict__ x, const float* __restrict__ w,
    const float* __restrict__ b, float* __restrict__ y,
    float* __restrict__ spart, float* __restrict__ sspart, int P,
    int Cout, int Hin, int Win, int Hout, int Wout) {
    int tx = threadIdx.x & 15, ty = threadIdx.x >> 4;
    int tilesX = Wout >> 4;
    int ow = (blockIdx.x % tilesX) * 16 + tx;
    int oh = (blockIdx.x / tilesX) * 16 + ty;
    int oc0 = blockIdx.y * OCPT;
    int n = blockIdx.z;

    int ih0 = oh * 2 - 1, iw0 = ow * 2 - 1;
    int off[9];
    float mm[9];
#pragma unroll
    for (int kh = 0; kh < 3; ++kh) {
        int ih = ih0 + kh;
        int ihc = min(max(ih, 0), Hin - 1);
        float mr = (ih >= 0 && ih < Hin) ? 1.f : 0.f;
#pragma unroll
        for (int kw = 0; kw < 3; ++kw) {
            int iw = iw0 + kw;
            int iwc = min(max(iw, 0), Win - 1);
            float mc = (iw >= 0 && iw < Win) ? 1.f : 0.f;
            off[kh * 3 + kw] = ihc * Win + iwc;
            mm[kh * 3 + kw] = mr * mc;
        }
    }

    float acc[OCPT];
#pragma unroll
    for (int j = 0; j < OCPT; ++j) acc[j] = 0.f;

    const float* xn = x + (size_t)n * CIN * Hin * Win;
    for (int ic0 = 0; ic0 < CIN; ic0 += ICB) {
        float v[ICB][9];
#pragma unroll
        for (int icl = 0; icl < ICB; ++icl) {
            const float* xp = xn + (size_t)(ic0 + icl) * Hin * Win;
#pragma unroll
            for (int t = 0; t < 9; ++t) v[icl][t] = xp[off[t]] * mm[t];
        }
#pragma unroll
        for (int icl = 0; icl < ICB; ++icl) {
            const float* wp = w + ((size_t)oc0 * CIN + ic0 + icl) * 9;
#pragma unroll
            for (int j = 0; j < OCPT; ++j) {
#pragma unroll
                for (int t = 0; t < 9; ++t)
                    acc[j] += v[icl][t] * wp[(size_t)j * CIN * 9 + t];
            }
        }
    }
    float sv[OCPT], ssv[OCPT];
#pragma unroll
    for (int j = 0; j < OCPT; ++j) {
        float r = acc[j] + b[oc0 + j];
        y[(((size_t)n * Cout + oc0 + j) * Hout + oh) * Wout + ow] = r;
        sv[j] = r;
        ssv[j] = r * r;
    }
    stats_block_store<OCPT>(sv, ssv, spart, sspart, P, blockIdx.x, n * Cout + oc0);
}

// ---------------- 3x3 s2 transposed conv, quad, prefetch, fused stats -------
// torch weight layout w[Cin][Cout][3][3]; output quad at (2qy,2qx).
// requires CIN % (2*ICB) == 0. No early return: clamped addrs + masks so all
// threads reach the stats barrier.
template <int CIN, int ICB, int OCPT>
__global__ __launch_bounds__(256) void convt3_v4s(
    const float* __restrict__ x, const float* __restrict__ w,
    const float* __restrict__ b, float* __restrict__ y,
    float* __restrict__ spart, float* __restrict__ sspart, int P,
    int Cout, int Hin, int Win, int Hout, int Wout) {
    int tx = threadIdx.x & 15, ty = threadIdx.x >> 4;
    int tilesX = IDIV(Win, 16);
    int qx = (blockIdx.x % tilesX) * 16 + tx;
    int qy = (blockIdx.x / tilesX) * 16 + ty;
    int oc0 = blockIdx.y * OCPT;
    int n = blockIdx.z;
    bool valid = (qx < Win) && (qy < Hin);
    int qxc = min(qx, Win - 1), qyc = min(qy, Hin - 1);
    bool xin = valid && (qx + 1 < Win), yin = valid && (qy + 1 < Hin);
    int o01 = xin ? 1 : 0, o10 = yin ? Win : 0;
    int o11 = o01 + o10;
    float m01 = xin ? 1.f : 0.f, m10 = yin ? 1.f : 0.f, m11 = m01 * m10;

    float a00[OCPT], a01[OCPT], a10[OCPT], a11[OCPT];
#pragma unroll
    for (int j = 0; j < OCPT; ++j) { a00[j] = a01[j] = a10[j] = a11[j] = 0.f; }

    const float* xn = x + ((size_t)n * CIN) * Hin * Win + (size_t)qyc * Win + qxc;
    const int HW = Hin * Win;

    float va[ICB][4], vb[ICB][4];
    auto load = [&](float (&v)[ICB][4], int ic0) {
#pragma unroll
        for (int icl = 0; icl < ICB; ++icl) {
            const float* xp = xn + (size_t)(ic0 + icl) * HW;
            v[icl][0] = xp[0];
            v[icl][1] = xp[o01] * m01;
            v[icl][2] = xp[o10] * m10;
            v[icl][3] = xp[o11] * m11;
        }
    };
    auto fma = [&](const float (&v)[ICB][4], int ic0) {
#pragma unroll
        for (int icl = 0; icl < ICB; ++icl) {
            const float* wp = w + ((size_t)(ic0 + icl) * Cout + oc0) * 9;
#pragma unroll
            for (int j = 0; j < OCPT; ++j) {
                const float* wj = wp + j * 9;
                float w0 = wj[0], w1 = wj[1], w2 = wj[2];
                float w3 = wj[3], w4 = wj[4], w5 = wj[5];
                float w6 = wj[6], w7 = wj[7], w8 = wj[8];
                a00[j] += w4 * v[icl][0];
                a01[j] += w5 * v[icl][0] + w3 * v[icl][1];
                a10[j] += w7 * v[icl][0] + w1 * v[icl][2];
                a11[j] += w8 * v[icl][0] + w6 * v[icl][1] + w2 * v[icl][2] + w0 * v[icl][3];
            }
        }
    };

    load(va, 0);
    for (int ic0 = 0; ic0 < CIN; ic0 += 2 * ICB) {
        load(vb, ic0 + ICB);
        fma(va, ic0);
        load(va, min(ic0 + 2 * ICB, CIN - ICB));
        fma(vb, ic0 + ICB);
    }

    int oh = 2 * qy, ow = 2 * qx;
    float sv[OCPT], ssv[OCPT];
#pragma unroll
    for (int j = 0; j < OCPT; ++j) {
        float s = 0.f, ss = 0.f;
        if (valid) {
            float bb = b[oc0 + j];
            float* yp = y + (((size_t)n * Cout + oc0 + j) * Hout + oh) * Wout + ow;
            float t00 = a00[j] + bb;
            yp[0] = t00; s += t00; ss += t00 * t00;
            if (xin) { float t = a01[j] + bb; yp[1] = t; s += t; ss += t * t; }
            if (yin) { float t = a10[j] + bb; yp[Wout] = t; s += t; ss += t * t; }
            if (xin && yin) { float t = a11[j] + bb; yp[Wout + 1] = t; s += t; ss += t * t; }
        }
        sv[j] = s; ssv[j] = ss;
    }
    stats_block_store<OCPT>(sv, ssv, spart, sspart, P, blockIdx.x, n * Cout + oc0);
}

// ---------------- inorm apply, float4 coalesced (plane % 4 == 0) ------------
__global__ void inorm_apply4(float* __restrict__ x, const float* __restrict__ mean,
                             const float* __restrict__ inv, int plane4) {
    int pc = blockIdx.y;
    int i = blockIdx.x * 256 + threadIdx.x;
    if (i >= plane4) return;
    float m = mean[pc], iv = inv[pc];
    float4* p = (float4*)(x + (size_t)pc * plane4 * 4);
    float4 v = p[i];
    v.x = fmaxf(0.f, (v.x - m) * iv);
    v.y = fmaxf(0.f, (v.y - m) * iv);
    v.z = fmaxf(0.f, (v.z - m) * iv);
    v.w = fmaxf(0.f, (v.w - m) * iv);
    p[i] = v;
}

// ---------------- inorm apply, 1 elem/thread coalesced (any plane) ----------
__global__ void inorm_apply1(float* __restrict__ x, const float* __restrict__ mean,
                             const float* __restrict__ inv, int plane) {
    int pc = blockIdx.y;
    int i = blockIdx.x * 256 + threadIdx.x;
    if (i >= plane) return;
    float m = mean[pc], iv = inv[pc];
    size_t idx = (size_t)pc * plane + i;
    x[idx] = fmaxf(0.f, (x[idx] - m) * iv);
}

// ---------------- segment mean (accum fused with L7 finalize) ---------------
__global__ void seg_zero(float* __restrict__ bins) {
    if (threadIdx.x < 128) bins[threadIdx.x] = 0.f;
}

// reads the 4 ic-split partials + bias, computes tanh inline; a7 never built.
__global__ void seg_accum_f(const float* __restrict__ part, const float* __restrict__ b,
                            const int* __restrict__ inst, float* __restrict__ bins,
                            int HW, size_t PS) {
    __shared__ float ls[128];  // 96 sums + 32 counts
    for (int i = threadIdx.x; i < 128; i += 256) ls[i] = 0.f;
    __syncthreads();
    int n = blockIdx.y;
    int i = blockIdx.x * 256 + threadIdx.x;
    if (i < HW) {
        int id = inst[(size_t)n * HW + i];
#pragma unroll
        for (int c = 0; c < 3; ++c) {
            size_t off = ((size_t)(n * 3 + c)) * HW + i;
            float v = part[off] + part[PS + off] + part[2 * PS + off] +
                      part[3 * PS + off] + b[c];
            atomicAdd(&ls[id * 3 + c], tanhf(v));
        }
        atomicAdd(&ls[96 + id], 1.0f);
    }
    __syncthreads();
    for (int i2 = threadIdx.x; i2 < 128; i2 += 256)
        if (ls[i2] != 0.f) atomicAdd(&bins[i2], ls[i2]);
}

__global__ void seg_scatter(const float* __restrict__ bins, const int* __restrict__ inst,
                            float* __restrict__ out, int HW) {
    int n = blockIdx.y;
    int i = blockIdx.x * 256 + threadIdx.x;
    if (i >= HW) return;
    int id = inst[(size_t)n * HW + i];
    float c = fmaxf(bins[96 + id], 1.0f);
    out[((size_t)n * 3 + 0) * HW + i] = bins[id * 3 + 0] / c;
    out[((size_t)n * 3 + 1) * HW + i] = bins[id * 3 + 1] / c;
    out[((size_t)n * 3 + 2) * HW + i] = bins[id * 3 + 2] / c;
}

// ---------------------------------------------------------------------------
extern "C" void kernel_launch(void* const* d_in, const int* in_sizes, int n_in,
                              void* d_out, int out_size, void* d_ws, size_t ws_size,
                              hipStream_t stream) {
    const float* x = (const float*)d_in[0];
    const int* inst = (const int*)d_in[1];
    const float* W[8];
    const float* B[8];
    for (int i = 0; i < 8; ++i) {
        W[i] = (const float*)d_in[2 + 2 * i];
        B[i] = (const float*)d_in[3 + 2 * i];
    }
    float* ws = (float*)d_ws;

    // End-aligned ping-pong arena (R2/R6 proven)
    const size_t S = 25165824;  // floats
    float* a0 = ws;                  // [8,32,256,256]
    float* a1 = ws + 16777216;       // [8,64,128,128]
    float* a2 = ws;                  // [8,128,64,64]
    float* a3 = ws + 23068672;       // [8,256,32,32]
    float* a4 = ws;                  // [8,128,63,63]
    float* a5 = ws + 17165824;       // [8,64,125,125]
    float* a6 = ws;                  // [8,32,249,249]  0 .. 15.87M
    float* PART = ws + 16000000;     // 4 x 1488024 floats (gap above a6)
    float* mean = ws + S;            // 2048
    float* inv = mean + 2048;        // 2048
    float* bins = inv + 2048;        // 128
    float* spart = bins + 128;       // 65536 (max nT*P = 256*256)
    float* sspart = spart + 65536;   // 65536

    // L0: 7x7 reflect, 3->32, 256. 8192 blocks, fused stats
    conv7_v3s<3, 8><<<dim3(256, 4, 8), 256, 0, stream>>>(
        x, W[0], B[0], a0, spart, sspart, 256, 32, 256, 256);
    stat_reduce_mi<<<dim3(256), 64, 0, stream>>>(spart, sspart, mean, inv, 256, 256, 1.f / 65536.f);
    inorm_apply4<<<dim3(IDIV(16384, 256), 256), 256, 0, stream>>>(a0, mean, inv, 16384);

    // L1: 3x3 s2, 32->64, 256->128. 4096 blocks, fused stats
    conv3s2_v3s<32, 4, 8><<<dim3(64, 8, 8), 256, 0, stream>>>(
        a0, W[1], B[1], a1, spart, sspart, 512, 64, 256, 256, 128, 128);
    stat_reduce_mi<<<dim3(512), 64, 0, stream>>>(spart, sspart, mean, inv, 512, 64, 1.f / 16384.f);
    inorm_apply4<<<dim3(IDIV(4096, 256), 512), 256, 0, stream>>>(a1, mean, inv, 4096);

    // L2: 3x3 s2, 64->128, 128->64. 2048 blocks, fused stats
    conv3s2_v3s<64, 4, 8><<<dim3(16, 16, 8), 256, 0, stream>>>(
        a1, W[2], B[2], a2, spart, sspart, 1024, 128, 128, 128, 64, 64);
    stat_reduce_mi<<<dim3(1024), 64, 0, stream>>>(spart, sspart, mean, inv, 1024, 16, 1.f / 4096.f);
    inorm_apply4<<<dim3(IDIV(1024, 256), 1024), 256, 0, stream>>>(a2, mean, inv, 1024);

    // L3: 3x3 s2, 128->256, 64->32. 1024 blocks, fused stats
    conv3s2_v3s<128, 4, 8><<<dim3(4, 32, 8), 256, 0, stream>>>(
        a2, W[3], B[3], a3, spart, sspart, 2048, 256, 64, 64, 32, 32);
    stat_reduce_mi<<<dim3(2048), 64, 0, stream>>>(spart, sspart, mean, inv, 2048, 4, 1.f / 1024.f);
    inorm_apply4<<<dim3(1, 2048), 256, 0, stream>>>(a3, mean, inv, 256);

    // L4: convT, 256->128, 32->63. ICB=8 deep prefetch (grid-limited layer)
    convt3_v4s<256, 8, 4><<<dim3(4, 32, 8), 256, 0, stream>>>(
        a3, W[4], B[4], a4, spart, sspart, 1024, 128, 32, 32, 63, 63);
    stat_reduce_mi<<<dim3(1024), 64, 0, stream>>>(spart, sspart, mean, inv, 1024, 4, 1.f / 3969.f);
    inorm_apply1<<<dim3(IDIV(3969, 256), 1024), 256, 0, stream>>>(a4, mean, inv, 3969);

    // L5: convT, 128->64, 63->125. 2048 blocks, fused stats
    convt3_v4s<128, 4, 4><<<dim3(16, 16, 8), 256, 0, stream>>>(
        a4, W[5], B[5], a5, spart, sspart, 512, 64, 63, 63, 125, 125);
    stat_reduce_mi<<<dim3(512), 64, 0, stream>>>(spart, sspart, mean, inv, 512, 16, 1.f / 15625.f);
    inorm_apply1<<<dim3(IDIV(15625, 256), 512), 256, 0, stream>>>(a5, mean, inv, 15625);

    // L6: convT, 64->32, 125->249. 4096 blocks, fused stats
    convt3_v4s<64, 4, 4><<<dim3(64, 8, 8), 256, 0, stream>>>(
        a5, W[6], B[6], a6, spart, sspart, 256, 32, 125, 125, 249, 249);
    stat_reduce_mi<<<dim3(256), 64, 0, stream>>>(spart, sspart, mean, inv, 256, 64, 1.f / 62001.f);
    inorm_apply1<<<dim3(IDIV(62001, 256), 256), 256, 0, stream>>>(a6, mean, inv, 62001);

    // L7: 7x7 reflect, 32->3, 249 — ic-split x4; finalize fused into seg_accum
    conv7_part<32, 8, 3><<<dim3(256, 4, 8), 256, 0, stream>>>(a6, W[7], PART, 1488024, 249, 249);

    // segment mean (accum reads partials + bias + tanh inline)
    seg_zero<<<1, 128, 0, stream>>>(bins);
    seg_accum_f<<<dim3(IDIV(62001, 256), 8), 256, 0, stream>>>(
        PART, B[7], inst, bins, 62001, 1488024);
    seg_scatter<<<dim3(IDIV(62001, 256), 8), 256, 0, stream>>>(bins, inst, (float*)d_out, 62001);
}

// Round 18
// 1439.625 us; speedup vs baseline: 1.2342x; 1.2342x over previous
//
#include <hip/hip_runtime.h>
#include <math.h>

// ---------------------------------------------------------------------------
// FeatureEncoder R18 = R16 (best, 1445us) + ONLY the seg-accum fusion from
// R17 (conv7_fin folded into seg_accum_f; a7 never materialized). R17's L4
// ICB=8 reverted — deep prefetch regressed L4 ~3x (VGPR 88 + redundant tail
// reloads); load-batch depth is a confirmed dead axis.
// ---------------------------------------------------------------------------

#define IDIV(a, b) (((a) + (b) - 1) / (b))

__device__ __forceinline__ int reflect_i(int i, int n) {
    i = i < 0 ? -i : i;
    return i >= n ? 2 * n - 2 - i : i;
}

// block-level (sum,sumsq) reduction for OCPT channels -> partial store
template <int OCPT>
__device__ __forceinline__ void stats_block_store(
    const float* sv, const float* ssv, float* __restrict__ spart,
    float* __restrict__ sspart, int P, int tile, int pc0) {
    __shared__ float redS[OCPT], redSS[OCPT];
    if (threadIdx.x < OCPT) { redS[threadIdx.x] = 0.f; redSS[threadIdx.x] = 0.f; }
    __syncthreads();
    int lane = threadIdx.x & 63;
#pragma unroll
    for (int j = 0; j < OCPT; ++j) {
        float s = sv[j], ss = ssv[j];
#pragma unroll
        for (int o = 32; o > 0; o >>= 1) {
            s += __shfl_down(s, o);
            ss += __shfl_down(ss, o);
        }
        if (lane == 0) { atomicAdd(&redS[j], s); atomicAdd(&redSS[j], ss); }  // LDS atomics
    }
    __syncthreads();
    if (threadIdx.x < OCPT) {
        spart[(size_t)tile * P + pc0 + threadIdx.x] = redS[threadIdx.x];
        sspart[(size_t)tile * P + pc0 + threadIdx.x] = redSS[threadIdx.x];
    }
}

// fold [nT][P] partials -> mean, inv (one wavefront per plane)
__global__ __launch_bounds__(64) void stat_reduce_mi(
    const float* __restrict__ sp, const float* __restrict__ ssp,
    float* __restrict__ mean, float* __restrict__ inv, int P, int nT,
    float rcp_plane) {
    int p = blockIdx.x;
    float a = 0.f, bsum = 0.f;
    for (int t = threadIdx.x; t < nT; t += 64) {
        a += sp[(size_t)t * P + p];
        bsum += ssp[(size_t)t * P + p];
    }
#pragma unroll
    for (int o = 32; o > 0; o >>= 1) {
        a += __shfl_down(a, o);
        bsum += __shfl_down(bsum, o);
    }
    if (threadIdx.x == 0) {
        float m = a * rcp_plane;
        float var = bsum * rcp_plane - m * m;
        mean[p] = m;
        inv[p] = rsqrtf(var + 1e-5f);
    }
}

// ---------------- 7x7 same-conv (L0: raw input), fused stats ----------------
template <int CIN, int OCPT>
__global__ __launch_bounds__(256) void conv7_v3s(
    const float* __restrict__ x, const float* __restrict__ w,
    const float* __restrict__ b, float* __restrict__ y,
    float* __restrict__ spart, float* __restrict__ sspart, int P,
    int Cout, int H, int W) {
    int tx = threadIdx.x & 15, ty = threadIdx.x >> 4;
    int tilesX = IDIV(W, 16);
    int ow = (blockIdx.x % tilesX) * 16 + tx;
    int oh = (blockIdx.x / tilesX) * 16 + ty;
    int oc0 = blockIdx.y * OCPT;
    int n = blockIdx.z;
    // exact-fit grid: no early return (barrier safety)

    int offr[7], iws[7];
#pragma unroll
    for (int k = 0; k < 7; ++k) {
        offr[k] = reflect_i(oh + k - 3, H) * W;
        iws[k] = reflect_i(ow + k - 3, W);
    }

    float acc[OCPT];
#pragma unroll
    for (int j = 0; j < OCPT; ++j) acc[j] = 0.f;

    const float* xn = x + (size_t)n * CIN * H * W;
    for (int ic = 0; ic < CIN; ++ic) {
        const float* xp = xn + (size_t)ic * H * W;
        float v[49];
#pragma unroll
        for (int kh = 0; kh < 7; ++kh) {
#pragma unroll
            for (int kw = 0; kw < 7; ++kw)
                v[kh * 7 + kw] = xp[offr[kh] + iws[kw]];
        }
        const float* wp = w + ((size_t)oc0 * CIN + ic) * 49;
#pragma unroll
        for (int j = 0; j < OCPT; ++j) {
#pragma unroll
            for (int t = 0; t < 49; ++t)
                acc[j] += v[t] * wp[(size_t)j * CIN * 49 + t];
        }
    }
    float sv[OCPT], ssv[OCPT];
#pragma unroll
    for (int j = 0; j < OCPT; ++j) {
        float r = acc[j] + b[oc0 + j];
        y[(((size_t)n * Cout + oc0 + j) * H + oh) * W + ow] = r;
        sv[j] = r;
        ssv[j] = r * r;
    }
    stats_block_store<OCPT>(sv, ssv, spart, sspart, P, blockIdx.x, n * Cout + oc0);
}

// ---------------- 7x7 conv, ic-split partial (L7) ----------------
template <int CINTOT, int ICPB, int OCPT>
__global__ __launch_bounds__(256) void conv7_part(
    const float* __restrict__ x, const float* __restrict__ w,
    float* __restrict__ part, size_t PS, int H, int W) {
    int tx = threadIdx.x & 15, ty = threadIdx.x >> 4;
    int tilesX = IDIV(W, 16);
    int ow = (blockIdx.x % tilesX) * 16 + tx;
    int oh = (blockIdx.x / tilesX) * 16 + ty;
    int ks = blockIdx.y;
    int n = blockIdx.z;
    if (ow >= W || oh >= H) return;

    int offr[7], iws[7];
#pragma unroll
    for (int k = 0; k < 7; ++k) {
        offr[k] = reflect_i(oh + k - 3, H) * W;
        iws[k] = reflect_i(ow + k - 3, W);
    }

    float acc[OCPT];
#pragma unroll
    for (int j = 0; j < OCPT; ++j) acc[j] = 0.f;

    const float* xn = x + (size_t)n * CINTOT * H * W;
    const int ic0 = ks * ICPB;
    for (int icl = 0; icl < ICPB; ++icl) {
        int ic = ic0 + icl;
        const float* xp = xn + (size_t)ic * H * W;
        float v[49];
#pragma unroll
        for (int kh = 0; kh < 7; ++kh) {
#pragma unroll
            for (int kw = 0; kw < 7; ++kw)
                v[kh * 7 + kw] = xp[offr[kh] + iws[kw]];
        }
        const float* wp = w + (size_t)ic * 49;
#pragma unroll
        for (int j = 0; j < OCPT; ++j) {
#pragma unroll
            for (int t = 0; t < 49; ++t)
                acc[j] += v[t] * wp[(size_t)j * CINTOT * 49 + t];
        }
    }
#pragma unroll
    for (int j = 0; j < OCPT; ++j)
        part[(size_t)ks * PS + (((size_t)n * OCPT + j) * H + oh) * W + ow] = acc[j];
}

// ---------------- 3x3 s2 conv, branchless batched loads, fused stats --------
template <int CIN, int ICB, int OCPT>
__global__ __launch_bounds__(256) void conv3s2_v3s(
    const float* __restrict__ x, const float* __restrict__ w,
    const float* __restrict__ b, float* __restrict__ y,
    float* __restrict__ spart, float* __restrict__ sspart, int P,
    int Cout, int Hin, int Win, int Hout, int Wout) {
    int tx = threadIdx.x & 15, ty = threadIdx.x >> 4;
    int tilesX = Wout >> 4;
    int ow = (blockIdx.x % tilesX) * 16 + tx;
    int oh = (blockIdx.x / tilesX) * 16 + ty;
    int oc0 = blockIdx.y * OCPT;
    int n = blockIdx.z;

    int ih0 = oh * 2 - 1, iw0 = ow * 2 - 1;
    int off[9];
    float mm[9];
#pragma unroll
    for (int kh = 0; kh < 3; ++kh) {
        int ih = ih0 + kh;
        int ihc = min(max(ih, 0), Hin - 1);
        float mr = (ih >= 0 && ih < Hin) ? 1.f : 0.f;
#pragma unroll
        for (int kw = 0; kw < 3; ++kw) {
            int iw = iw0 + kw;
            int iwc = min(max(iw, 0), Win - 1);
            float mc = (iw >= 0 && iw < Win) ? 1.f : 0.f;
            off[kh * 3 + kw] = ihc * Win + iwc;
            mm[kh * 3 + kw] = mr * mc;
        }
    }

    float acc[OCPT];
#pragma unroll
    for (int j = 0; j < OCPT; ++j) acc[j] = 0.f;

    const float* xn = x + (size_t)n * CIN * Hin * Win;
    for (int ic0 = 0; ic0 < CIN; ic0 += ICB) {
        float v[ICB][9];
#pragma unroll
        for (int icl = 0; icl < ICB; ++icl) {
            const float* xp = xn + (size_t)(ic0 + icl) * Hin * Win;
#pragma unroll
            for (int t = 0; t < 9; ++t) v[icl][t] = xp[off[t]] * mm[t];
        }
#pragma unroll
        for (int icl = 0; icl < ICB; ++icl) {
            const float* wp = w + ((size_t)oc0 * CIN + ic0 + icl) * 9;
#pragma unroll
            for (int j = 0; j < OCPT; ++j) {
#pragma unroll
                for (int t = 0; t < 9; ++t)
                    acc[j] += v[icl][t] * wp[(size_t)j * CIN * 9 + t];
            }
        }
    }
    float sv[OCPT], ssv[OCPT];
#pragma unroll
    for (int j = 0; j < OCPT; ++j) {
        float r = acc[j] + b[oc0 + j];
        y[(((size_t)n * Cout + oc0 + j) * Hout + oh) * Wout + ow] = r;
        sv[j] = r;
        ssv[j] = r * r;
    }
    stats_block_store<OCPT>(sv, ssv, spart, sspart, P, blockIdx.x, n * Cout + oc0);
}

// ---------------- 3x3 s2 transposed conv, quad, prefetch, fused stats -------
// torch weight layout w[Cin][Cout][3][3]; output quad at (2qy,2qx).
// requires CIN % (2*ICB) == 0. No early return: clamped addrs + masks so all
// threads reach the stats barrier.
template <int CIN, int ICB, int OCPT>
__global__ __launch_bounds__(256) void convt3_v4s(
    const float* __restrict__ x, const float* __restrict__ w,
    const float* __restrict__ b, float* __restrict__ y,
    float* __restrict__ spart, float* __restrict__ sspart, int P,
    int Cout, int Hin, int Win, int Hout, int Wout) {
    int tx = threadIdx.x & 15, ty = threadIdx.x >> 4;
    int tilesX = IDIV(Win, 16);
    int qx = (blockIdx.x % tilesX) * 16 + tx;
    int qy = (blockIdx.x / tilesX) * 16 + ty;
    int oc0 = blockIdx.y * OCPT;
    int n = blockIdx.z;
    bool valid = (qx < Win) && (qy < Hin);
    int qxc = min(qx, Win - 1), qyc = min(qy, Hin - 1);
    bool xin = valid && (qx + 1 < Win), yin = valid && (qy + 1 < Hin);
    int o01 = xin ? 1 : 0, o10 = yin ? Win : 0;
    int o11 = o01 + o10;
    float m01 = xin ? 1.f : 0.f, m10 = yin ? 1.f : 0.f, m11 = m01 * m10;

    float a00[OCPT], a01[OCPT], a10[OCPT], a11[OCPT];
#pragma unroll
    for (int j = 0; j < OCPT; ++j) { a00[j] = a01[j] = a10[j] = a11[j] = 0.f; }

    const float* xn = x + ((size_t)n * CIN) * Hin * Win + (size_t)qyc * Win + qxc;
    const int HW = Hin * Win;

    float va[ICB][4], vb[ICB][4];
    auto load = [&](float (&v)[ICB][4], int ic0) {
#pragma unroll
        for (int icl = 0; icl < ICB; ++icl) {
            const float* xp = xn + (size_t)(ic0 + icl) * HW;
            v[icl][0] = xp[0];
            v[icl][1] = xp[o01] * m01;
            v[icl][2] = xp[o10] * m10;
            v[icl][3] = xp[o11] * m11;
        }
    };
    auto fma = [&](const float (&v)[ICB][4], int ic0) {
#pragma unroll
        for (int icl = 0; icl < ICB; ++icl) {
            const float* wp = w + ((size_t)(ic0 + icl) * Cout + oc0) * 9;
#pragma unroll
            for (int j = 0; j < OCPT; ++j) {
                const float* wj = wp + j * 9;
                float w0 = wj[0], w1 = wj[1], w2 = wj[2];
                float w3 = wj[3], w4 = wj[4], w5 = wj[5];
                float w6 = wj[6], w7 = wj[7], w8 = wj[8];
                a00[j] += w4 * v[icl][0];
                a01[j] += w5 * v[icl][0] + w3 * v[icl][1];
                a10[j] += w7 * v[icl][0] + w1 * v[icl][2];
                a11[j] += w8 * v[icl][0] + w6 * v[icl][1] + w2 * v[icl][2] + w0 * v[icl][3];
            }
        }
    };

    load(va, 0);
    for (int ic0 = 0; ic0 < CIN; ic0 += 2 * ICB) {
        load(vb, ic0 + ICB);
        fma(va, ic0);
        load(va, min(ic0 + 2 * ICB, CIN - ICB));
        fma(vb, ic0 + ICB);
    }

    int oh = 2 * qy, ow = 2 * qx;
    float sv[OCPT], ssv[OCPT];
#pragma unroll
    for (int j = 0; j < OCPT; ++j) {
        float s = 0.f, ss = 0.f;
        if (valid) {
            float bb = b[oc0 + j];
            float* yp = y + (((size_t)n * Cout + oc0 + j) * Hout + oh) * Wout + ow;
            float t00 = a00[j] + bb;
            yp[0] = t00; s += t00; ss += t00 * t00;
            if (xin) { float t = a01[j] + bb; yp[1] = t; s += t; ss += t * t; }
            if (yin) { float t = a10[j] + bb; yp[Wout] = t; s += t; ss += t * t; }
            if (xin && yin) { float t = a11[j] + bb; yp[Wout + 1] = t; s += t; ss += t * t; }
        }
        sv[j] = s; ssv[j] = ss;
    }
    stats_block_store<OCPT>(sv, ssv, spart, sspart, P, blockIdx.x, n * Cout + oc0);
}

// ---------------- inorm apply, float4 coalesced (plane % 4 == 0) ------------
__global__ void inorm_apply4(float* __restrict__ x, const float* __restrict__ mean,
                             const float* __restrict__ inv, int plane4) {
    int pc = blockIdx.y;
    int i = blockIdx.x * 256 + threadIdx.x;
    if (i >= plane4) return;
    float m = mean[pc], iv = inv[pc];
    float4* p = (float4*)(x + (size_t)pc * plane4 * 4);
    float4 v = p[i];
    v.x = fmaxf(0.f, (v.x - m) * iv);
    v.y = fmaxf(0.f, (v.y - m) * iv);
    v.z = fmaxf(0.f, (v.z - m) * iv);
    v.w = fmaxf(0.f, (v.w - m) * iv);
    p[i] = v;
}

// ---------------- inorm apply, 1 elem/thread coalesced (any plane) ----------
__global__ void inorm_apply1(float* __restrict__ x, const float* __restrict__ mean,
                             const float* __restrict__ inv, int plane) {
    int pc = blockIdx.y;
    int i = blockIdx.x * 256 + threadIdx.x;
    if (i >= plane) return;
    float m = mean[pc], iv = inv[pc];
    size_t idx = (size_t)pc * plane + i;
    x[idx] = fmaxf(0.f, (x[idx] - m) * iv);
}

// ---------------- segment mean (accum fused with L7 finalize) ---------------
__global__ void seg_zero(float* __restrict__ bins) {
    if (threadIdx.x < 128) bins[threadIdx.x] = 0.f;
}

// reads the 4 ic-split partials + bias, computes tanh inline; a7 never built.
__global__ void seg_accum_f(const float* __restrict__ part, const float* __restrict__ b,
                            const int* __restrict__ inst, float* __restrict__ bins,
                            int HW, size_t PS) {
    __shared__ float ls[128];  // 96 sums + 32 counts
    for (int i = threadIdx.x; i < 128; i += 256) ls[i] = 0.f;
    __syncthreads();
    int n = blockIdx.y;
    int i = blockIdx.x * 256 + threadIdx.x;
    if (i < HW) {
        int id = inst[(size_t)n * HW + i];
#pragma unroll
        for (int c = 0; c < 3; ++c) {
            size_t off = ((size_t)(n * 3 + c)) * HW + i;
            float v = part[off] + part[PS + off] + part[2 * PS + off] +
                      part[3 * PS + off] + b[c];
            atomicAdd(&ls[id * 3 + c], tanhf(v));
        }
        atomicAdd(&ls[96 + id], 1.0f);
    }
    __syncthreads();
    for (int i2 = threadIdx.x; i2 < 128; i2 += 256)
        if (ls[i2] != 0.f) atomicAdd(&bins[i2], ls[i2]);
}

__global__ void seg_scatter(const float* __restrict__ bins, const int* __restrict__ inst,
                            float* __restrict__ out, int HW) {
    int n = blockIdx.y;
    int i = blockIdx.x * 256 + threadIdx.x;
    if (i >= HW) return;
    int id = inst[(size_t)n * HW + i];
    float c = fmaxf(bins[96 + id], 1.0f);
    out[((size_t)n * 3 + 0) * HW + i] = bins[id * 3 + 0] / c;
    out[((size_t)n * 3 + 1) * HW + i] = bins[id * 3 + 1] / c;
    out[((size_t)n * 3 + 2) * HW + i] = bins[id * 3 + 2] / c;
}

// ---------------------------------------------------------------------------
extern "C" void kernel_launch(void* const* d_in, const int* in_sizes, int n_in,
                              void* d_out, int out_size, void* d_ws, size_t ws_size,
                              hipStream_t stream) {
    const float* x = (const float*)d_in[0];
    const int* inst = (const int*)d_in[1];
    const float* W[8];
    const float* B[8];
    for (int i = 0; i < 8; ++i) {
        W[i] = (const float*)d_in[2 + 2 * i];
        B[i] = (const float*)d_in[3 + 2 * i];
    }
    float* ws = (float*)d_ws;

    // End-aligned ping-pong arena (R2/R6 proven)
    const size_t S = 25165824;  // floats
    float* a0 = ws;                  // [8,32,256,256]
    float* a1 = ws + 16777216;       // [8,64,128,128]
    float* a2 = ws;                  // [8,128,64,64]
    float* a3 = ws + 23068672;       // [8,256,32,32]
    float* a4 = ws;                  // [8,128,63,63]
    float* a5 = ws + 17165824;       // [8,64,125,125]
    float* a6 = ws;                  // [8,32,249,249]  0 .. 15.87M
    float* PART = ws + 16000000;     // 4 x 1488024 floats (gap above a6)
    float* mean = ws + S;            // 2048
    float* inv = mean + 2048;        // 2048
    float* bins = inv + 2048;        // 128
    float* spart = bins + 128;       // 65536 (max nT*P = 256*256)
    float* sspart = spart + 65536;   // 65536

    // L0: 7x7 reflect, 3->32, 256. 8192 blocks, fused stats
    conv7_v3s<3, 8><<<dim3(256, 4, 8), 256, 0, stream>>>(
        x, W[0], B[0], a0, spart, sspart, 256, 32, 256, 256);
    stat_reduce_mi<<<dim3(256), 64, 0, stream>>>(spart, sspart, mean, inv, 256, 256, 1.f / 65536.f);
    inorm_apply4<<<dim3(IDIV(16384, 256), 256), 256, 0, stream>>>(a0, mean, inv, 16384);

    // L1: 3x3 s2, 32->64, 256->128. 4096 blocks, fused stats
    conv3s2_v3s<32, 4, 8><<<dim3(64, 8, 8), 256, 0, stream>>>(
        a0, W[1], B[1], a1, spart, sspart, 512, 64, 256, 256, 128, 128);
    stat_reduce_mi<<<dim3(512), 64, 0, stream>>>(spart, sspart, mean, inv, 512, 64, 1.f / 16384.f);
    inorm_apply4<<<dim3(IDIV(4096, 256), 512), 256, 0, stream>>>(a1, mean, inv, 4096);

    // L2: 3x3 s2, 64->128, 128->64. 2048 blocks, fused stats
    conv3s2_v3s<64, 4, 8><<<dim3(16, 16, 8), 256, 0, stream>>>(
        a1, W[2], B[2], a2, spart, sspart, 1024, 128, 128, 128, 64, 64);
    stat_reduce_mi<<<dim3(1024), 64, 0, stream>>>(spart, sspart, mean, inv, 1024, 16, 1.f / 4096.f);
    inorm_apply4<<<dim3(IDIV(1024, 256), 1024), 256, 0, stream>>>(a2, mean, inv, 1024);

    // L3: 3x3 s2, 128->256, 64->32. 1024 blocks, fused stats
    conv3s2_v3s<128, 4, 8><<<dim3(4, 32, 8), 256, 0, stream>>>(
        a2, W[3], B[3], a3, spart, sspart, 2048, 256, 64, 64, 32, 32);
    stat_reduce_mi<<<dim3(2048), 64, 0, stream>>>(spart, sspart, mean, inv, 2048, 4, 1.f / 1024.f);
    inorm_apply4<<<dim3(1, 2048), 256, 0, stream>>>(a3, mean, inv, 256);

    // L4: convT, 256->128, 32->63. ICB=4 (R16-proven), fused stats
    convt3_v4s<256, 4, 4><<<dim3(4, 32, 8), 256, 0, stream>>>(
        a3, W[4], B[4], a4, spart, sspart, 1024, 128, 32, 32, 63, 63);
    stat_reduce_mi<<<dim3(1024), 64, 0, stream>>>(spart, sspart, mean, inv, 1024, 4, 1.f / 3969.f);
    inorm_apply1<<<dim3(IDIV(3969, 256), 1024), 256, 0, stream>>>(a4, mean, inv, 3969);

    // L5: convT, 128->64, 63->125. 2048 blocks, fused stats
    convt3_v4s<128, 4, 4><<<dim3(16, 16, 8), 256, 0, stream>>>(
        a4, W[5], B[5], a5, spart, sspart, 512, 64, 63, 63, 125, 125);
    stat_reduce_mi<<<dim3(512), 64, 0, stream>>>(spart, sspart, mean, inv, 512, 16, 1.f / 15625.f);
    inorm_apply1<<<dim3(IDIV(15625, 256), 512), 256, 0, stream>>>(a5, mean, inv, 15625);

    // L6: convT, 64->32, 125->249. 4096 blocks, fused stats
    convt3_v4s<64, 4, 4><<<dim3(64, 8, 8), 256, 0, stream>>>(
        a5, W[6], B[6], a6, spart, sspart, 256, 32, 125, 125, 249, 249);
    stat_reduce_mi<<<dim3(256), 64, 0, stream>>>(spart, sspart, mean, inv, 256, 64, 1.f / 62001.f);
    inorm_apply1<<<dim3(IDIV(62001, 256), 256), 256, 0, stream>>>(a6, mean, inv, 62001);

    // L7: 7x7 reflect, 32->3, 249 — ic-split x4; finalize fused into seg_accum
    conv7_part<32, 8, 3><<<dim3(256, 4, 8), 256, 0, stream>>>(a6, W[7], PART, 1488024, 249, 249);

    // segment mean (accum reads partials + bias + tanh inline)
    seg_zero<<<1, 128, 0, stream>>>(bins);
    seg_accum_f<<<dim3(IDIV(62001, 256), 8), 256, 0, stream>>>(
        PART, B[7], inst, bins, 62001, 1488024);
    seg_scatter<<<dim3(IDIV(62001, 256), 8), 256, 0, stream>>>(bins, inst, (float*)d_out, 62001);
}